// Round 14
// baseline (302.702 us; speedup 1.0000x reference)
//
#include <hip/hip_runtime.h>
#include <hip/hip_bf16.h>
#include <math.h>

// Problem constants (from reference)
#define N_NODES  100000
#define N_EDGES  1200000
#define N_GRAPHS 100
#define NPB      512                    // nodes per bucket (node >> 9)
#define NBK      196                    // ceil(100000/512)
#define BA       256                    // blocks for hist/scatter passes
#define PARTS    16                     // pooling partials per graph

// ---------------------------------------------------------------------------
// CSR build as a 2-level counting sort — ZERO global atomics.
// ---------------------------------------------------------------------------
__global__ __launch_bounds__(1024) void k_hist(
    const int* __restrict__ dst, int* __restrict__ hcnt, int e) {
    __shared__ int hist[NBK];
    int blk = blockIdx.x;
    for (int j = threadIdx.x; j < NBK; j += 1024) hist[j] = 0;
    __syncthreads();
    int per = (e + BA - 1) / BA;
    int beg = blk * per;
    int end = beg + per < e ? beg + per : e;
    for (int i = beg + threadIdx.x; i < end; i += 1024)
        atomicAdd(&hist[dst[i] >> 9], 1);
    __syncthreads();
    for (int j = threadIdx.x; j < NBK; j += 1024) hcnt[blk * NBK + j] = hist[j];
}

__global__ __launch_bounds__(256) void k_bstart(
    const int* __restrict__ hcnt, int* __restrict__ bstart,
    int* __restrict__ row_ptr, int e) {
    int b = threadIdx.x;
    int s = 0;
    if (b < NBK) {
        #pragma unroll 8
        for (int blk = 0; blk < BA; blk++) s += hcnt[blk * NBK + b];
    }
    __shared__ int sc[256];
    sc[b] = s;
    __syncthreads();
    for (int d = 1; d < 256; d <<= 1) {
        int u = (b >= d) ? sc[b - d] : 0;
        __syncthreads();
        sc[b] += u;
        __syncthreads();
    }
    if (b < NBK) bstart[b] = sc[b] - s;  // exclusive
    if (b == 0) { bstart[NBK] = e; row_ptr[N_NODES] = e; }
}

__global__ __launch_bounds__(256) void k_bdist(
    int* __restrict__ hcnt, const int* __restrict__ bstart) {
    int b = blockIdx.x, t = threadIdx.x;
    int v = hcnt[t * NBK + b];
    __shared__ int sc[256];
    sc[t] = v;
    __syncthreads();
    for (int d = 1; d < 256; d <<= 1) {
        int u = (t >= d) ? sc[t - d] : 0;
        __syncthreads();
        sc[t] += u;
        __syncthreads();
    }
    hcnt[t * NBK + b] = bstart[b] + (sc[t] - v);
}

__global__ __launch_bounds__(1024) void k_scatter(
    const int* __restrict__ src, const int* __restrict__ dst,
    const int* __restrict__ hcnt, int2* __restrict__ pairs, int e) {
    __shared__ int lbase[NBK];
    __shared__ int cnt[NBK];
    int blk = blockIdx.x;
    for (int j = threadIdx.x; j < NBK; j += 1024) {
        lbase[j] = hcnt[blk * NBK + j];
        cnt[j] = 0;
    }
    __syncthreads();
    int per = (e + BA - 1) / BA;
    int beg = blk * per;
    int end = beg + per < e ? beg + per : e;
    for (int i = beg + threadIdx.x; i < end; i += 1024) {
        int d = dst[i], s = src[i];
        int b = d >> 9;
        int r = atomicAdd(&cnt[b], 1);
        pairs[lbase[b] + r] = make_int2(d, s);
    }
}

__global__ __launch_bounds__(512) void k_bucket(
    const int2* __restrict__ pairs, const int* __restrict__ bstart,
    const float* __restrict__ x,
    int* __restrict__ row_ptr, float* __restrict__ dinv,
    float* __restrict__ y0, int* __restrict__ csr_src, int n) {
    __shared__ int hist[NPB];
    __shared__ int labs[NPB];
    __shared__ int wsum[8], woff[8];
    int b = blockIdx.x, t = threadIdx.x;
    int beg = bstart[b], end = bstart[b + 1];
    hist[t] = 0;
    __syncthreads();
    for (int i = beg + t; i < end; i += 512)
        atomicAdd(&hist[pairs[i].x & (NPB - 1)], 1);
    __syncthreads();
    int v = hist[t];
    int lane = t & 63, w = t >> 6;
    int inc = v;
    #pragma unroll
    for (int d = 1; d < 64; d <<= 1) {
        int u = __shfl_up(inc, d);
        if (lane >= d) inc += u;
    }
    if (lane == 63) wsum[w] = inc;
    __syncthreads();
    if (t == 0) {
        int s = 0;
        #pragma unroll
        for (int k = 0; k < 8; k++) { woff[k] = s; s += wsum[k]; }
    }
    __syncthreads();
    int excl = woff[w] + inc - v;
    labs[t] = beg + excl;
    int node = (b << 9) + t;
    if (node < n) {
        row_ptr[node] = beg + excl;
        float di = rsqrtf((float)(v + 1));   // +1 self loop
        dinv[node] = di;
        float4 q0, q1;
        q0.x = x[(size_t)node * 5 + 0] * di;
        q0.y = x[(size_t)node * 5 + 1] * di;
        q0.z = x[(size_t)node * 5 + 2] * di;
        q0.w = x[(size_t)node * 5 + 3] * di;
        q1.x = x[(size_t)node * 5 + 4] * di;
        q1.y = 0.f; q1.z = 0.f; q1.w = 0.f;
        *(float4*)&y0[(size_t)node * 8]     = q0;
        *(float4*)&y0[(size_t)node * 8 + 4] = q1;
    }
    __syncthreads();
    hist[t] = 0;
    __syncthreads();
    for (int i = beg + t; i < end; i += 512) {
        int2 p = pairs[i];
        int j = p.x & (NPB - 1);
        int r = atomicAdd(&hist[j], 1);
        csr_src[labs[j] + r] = p.y;
    }
}

// ---------------------------------------------------------------------------
// Layer 1: s0 = (A+I) y0;  h1 = relu((dinv*s0)@W1 + b1);  y1 = dinv*h1  [N,32]
// ---------------------------------------------------------------------------
__global__ __launch_bounds__(256) void k_agg1(
    const int* __restrict__ row_ptr, const int* __restrict__ csr_src,
    const float* __restrict__ y0, const float* __restrict__ dinv,
    const float* __restrict__ W1, const float* __restrict__ b1,
    float* __restrict__ y1, int n) {
    int wave = (blockIdx.x * blockDim.x + threadIdx.x) >> 6;
    if (wave >= n) return;
    int lane = threadIdx.x & 63;
    int f = lane & 7, ec = lane >> 3;
    int start = row_ptr[wave], end = row_ptr[wave + 1];
    float acc = 0.f;
    for (int e = start + ec; e < end; e += 8) {
        int s = csr_src[e];
        acc += y0[(size_t)s * 8 + f];
    }
    if (ec == 0) acc += y0[(size_t)wave * 8 + f];   // self loop
    acc += __shfl_down(acc, 32);
    acc += __shfl_down(acc, 16);
    acc += __shfl_down(acc, 8);
    float di = dinv[wave];
    float s0[5];
    #pragma unroll
    for (int k = 0; k < 5; k++) s0[k] = __shfl(acc, k) * di;
    int fo = lane & 31;
    float hv = b1[fo];
    #pragma unroll
    for (int k = 0; k < 5; k++) hv += s0[k] * W1[k * 32 + fo];
    hv = hv > 0.f ? hv : 0.f;
    if (lane < 32) y1[(size_t)wave * 32 + lane] = hv * di;
}

// ---------------------------------------------------------------------------
// Layer 2 gather only:  sv = dinv * ((A+I) y1)   [N,32]
// ---------------------------------------------------------------------------
__global__ __launch_bounds__(256) void k_agg2g(
    const int* __restrict__ row_ptr, const int* __restrict__ csr_src,
    const float* __restrict__ y1, const float* __restrict__ dinv,
    float* __restrict__ sv, int n) {
    int wave = (blockIdx.x * blockDim.x + threadIdx.x) >> 6;
    if (wave >= n) return;
    int lane = threadIdx.x & 63;
    int ec = lane >> 3, fq = lane & 7;
    int start = row_ptr[wave], end = row_ptr[wave + 1];
    float4 a0 = make_float4(0.f, 0.f, 0.f, 0.f);
    float4 a1 = make_float4(0.f, 0.f, 0.f, 0.f);
    int e = start + ec;
    for (; e + 8 < end; e += 16) {
        int s0 = csr_src[e], s1 = csr_src[e + 8];
        float4 v0 = *(const float4*)&y1[(size_t)s0 * 32 + fq * 4];
        float4 v1 = *(const float4*)&y1[(size_t)s1 * 32 + fq * 4];
        a0.x += v0.x; a0.y += v0.y; a0.z += v0.z; a0.w += v0.w;
        a1.x += v1.x; a1.y += v1.y; a1.z += v1.z; a1.w += v1.w;
    }
    for (; e < end; e += 8) {
        int s0 = csr_src[e];
        float4 v0 = *(const float4*)&y1[(size_t)s0 * 32 + fq * 4];
        a0.x += v0.x; a0.y += v0.y; a0.z += v0.z; a0.w += v0.w;
    }
    a0.x += a1.x; a0.y += a1.y; a0.z += a1.z; a0.w += a1.w;
    if (ec == 0) {   // self loop
        float4 sl = *(const float4*)&y1[(size_t)wave * 32 + fq * 4];
        a0.x += sl.x; a0.y += sl.y; a0.z += sl.z; a0.w += sl.w;
    }
    a0.x += __shfl_down(a0.x, 32); a0.y += __shfl_down(a0.y, 32);
    a0.z += __shfl_down(a0.z, 32); a0.w += __shfl_down(a0.w, 32);
    a0.x += __shfl_down(a0.x, 16); a0.y += __shfl_down(a0.y, 16);
    a0.z += __shfl_down(a0.z, 16); a0.w += __shfl_down(a0.w, 16);
    a0.x += __shfl_down(a0.x, 8);  a0.y += __shfl_down(a0.y, 8);
    a0.z += __shfl_down(a0.z, 8);  a0.w += __shfl_down(a0.w, 8);
    if (lane < 8) {
        float di = dinv[wave];
        float4 r;
        r.x = a0.x * di; r.y = a0.y * di; r.z = a0.z * di; r.w = a0.w * di;
        *(float4*)&sv[(size_t)wave * 32 + fq * 4] = r;
    }
}

// ---------------------------------------------------------------------------
// Fused dense part of layer 2 as register-tiled f32 GEMM, 128-node tiles:
//   h2 = relu(sv @ W2 + b2)   [128 x 64]   (kept transposed in LDS)
//   h  = h2 @ nn1W + nn1b     [128 x 124]
// 512 threads, thread-tile 4 nodes x 8 feats. ONE 33.8KB LDS buffer (svT
// aliased to h2T across a barrier); W2 and nn1W read from global (identical
// addresses across blocks -> L2-broadcast). 128-node tiles halve the
// per-block-redundant weight traffic vs 64-node tiles (R13 showed occupancy
// alone didn't move the needle -> L2 weight-broadcast is the suspect), and
// 33.8KB LDS allows 4 blocks/CU = 32 waves = 100% occupancy cap.
// ---------------------------------------------------------------------------
#define LTS2 132   // padded row stride (128 nodes + 4), x4B = 16B-aligned
__global__ __launch_bounds__(512) void k_l2mm(
    const float* __restrict__ sv, const float* __restrict__ W2,
    const float* __restrict__ b2, const float* __restrict__ nn1W,
    const float* __restrict__ nn1b, float* __restrict__ h, int n) {
    __shared__ float lsT[64 * LTS2];   // svT[32][LTS2] then h2T[64][LTS2], 33.8 KB

    int tid = threadIdx.x;
    int nb = blockIdx.x * 128;

    // stage sv tile transposed: svT[k][node] = lsT[k*LTS2 + node]
    {
        int node = tid >> 2, kq = (tid & 3) * 8;   // 128 nodes x 4 threads
        float4 v0, v1;
        if (nb + node < n) {
            v0 = *(const float4*)&sv[(size_t)(nb + node) * 32 + kq];
            v1 = *(const float4*)&sv[(size_t)(nb + node) * 32 + kq + 4];
        } else {
            v0 = make_float4(0.f, 0.f, 0.f, 0.f); v1 = v0;
        }
        lsT[(kq + 0) * LTS2 + node] = v0.x;
        lsT[(kq + 1) * LTS2 + node] = v0.y;
        lsT[(kq + 2) * LTS2 + node] = v0.z;
        lsT[(kq + 3) * LTS2 + node] = v0.w;
        lsT[(kq + 4) * LTS2 + node] = v1.x;
        lsT[(kq + 5) * LTS2 + node] = v1.y;
        lsT[(kq + 6) * LTS2 + node] = v1.z;
        lsT[(kq + 7) * LTS2 + node] = v1.w;
    }
    __syncthreads();

    int tf = tid & 15;   // feature quad 0..15
    int tn = tid >> 4;   // node quad 0..31

    // GEMM1: c1[i][j] = sum_k svT[k][tn*4+i] * W2[k][tf*4+j]  (W2 from L2)
    float c1[4][4] = {};
    #pragma unroll 4
    for (int k = 0; k < 32; k++) {
        float4 a = *(const float4*)&lsT[k * LTS2 + tn * 4];
        float4 w = *(const float4*)&W2[k * 64 + tf * 4];
        const float av[4] = {a.x, a.y, a.z, a.w};
        const float wv[4] = {w.x, w.y, w.z, w.w};
        #pragma unroll
        for (int i = 0; i < 4; i++)
            #pragma unroll
            for (int j = 0; j < 4; j++) c1[i][j] += av[i] * wv[j];
    }
    __syncthreads();   // done reading svT -> safe to overwrite with h2T
    // relu(+b2), write h2 transposed: h2T[f][node]
    {
        float4 bb = *(const float4*)&b2[tf * 4];
        const float bv[4] = {bb.x, bb.y, bb.z, bb.w};
        #pragma unroll
        for (int j = 0; j < 4; j++) {
            float4 col;
            col.x = fmaxf(c1[0][j] + bv[j], 0.f);
            col.y = fmaxf(c1[1][j] + bv[j], 0.f);
            col.z = fmaxf(c1[2][j] + bv[j], 0.f);
            col.w = fmaxf(c1[3][j] + bv[j], 0.f);
            *(float4*)&lsT[(tf * 4 + j) * LTS2 + tn * 4] = col;
        }
    }
    __syncthreads();

    // GEMM2: weights straight from global (L2-broadcast, same addrs each block)
    float c2a[4][4] = {}, c2b[4][4] = {};
    #pragma unroll 2
    for (int k = 0; k < 64; k++) {
        float4 a = *(const float4*)&lsT[k * LTS2 + tn * 4];
        float4 w1 = *(const float4*)&nn1W[k * 124 + tf * 4];
        float4 w2 = make_float4(0.f, 0.f, 0.f, 0.f);
        if (tf < 15) w2 = *(const float4*)&nn1W[k * 124 + 64 + tf * 4];
        const float av[4] = {a.x, a.y, a.z, a.w};
        const float w1v[4] = {w1.x, w1.y, w1.z, w1.w};
        const float w2v[4] = {w2.x, w2.y, w2.z, w2.w};
        #pragma unroll
        for (int i = 0; i < 4; i++)
            #pragma unroll
            for (int j = 0; j < 4; j++) {
                c2a[i][j] += av[i] * w1v[j];
                c2b[i][j] += av[i] * w2v[j];
            }
    }
    {
        float4 ba = *(const float4*)&nn1b[tf * 4];
        const float bav[4] = {ba.x, ba.y, ba.z, ba.w};
        float bbv[4] = {0.f, 0.f, 0.f, 0.f};
        if (tf < 15) {
            float4 bb = *(const float4*)&nn1b[64 + tf * 4];
            bbv[0] = bb.x; bbv[1] = bb.y; bbv[2] = bb.z; bbv[3] = bb.w;
        }
        #pragma unroll
        for (int i = 0; i < 4; i++) {
            int node = nb + tn * 4 + i;
            if (node >= n) break;
            float4 oa, ob;
            oa.x = c2a[i][0] + bav[0]; oa.y = c2a[i][1] + bav[1];
            oa.z = c2a[i][2] + bav[2]; oa.w = c2a[i][3] + bav[3];
            *(float4*)&h[(size_t)node * 124 + tf * 4] = oa;
            if (tf < 15) {
                ob.x = c2b[i][0] + bbv[0]; ob.y = c2b[i][1] + bbv[1];
                ob.z = c2b[i][2] + bbv[2]; ob.w = c2b[i][3] + bbv[3];
                *(float4*)&h[(size_t)node * 124 + 64 + tf * 4] = ob;
            }
        }
    }
}

// ---------------------------------------------------------------------------
// Pooling phase A: G*PARTS blocks; block (g,r) reduces an interleaved slice
// of graph g's contiguous node range into partial[g][r][128] (max/min/sum).
// ---------------------------------------------------------------------------
__global__ __launch_bounds__(512) void k_pool_a(
    const float* __restrict__ h, const int* __restrict__ batch,
    float* __restrict__ pmax, float* __restrict__ pmin, float* __restrict__ psum,
    int n) {
    int g = blockIdx.x / PARTS, r = blockIdx.x % PARTS;
    __shared__ int sb[2];
    if (threadIdx.x < 2) {
        int target = g + threadIdx.x;
        int lo = 0, hi = n;
        while (lo < hi) {
            int mid = (lo + hi) >> 1;
            if (batch[mid] < target) lo = mid + 1; else hi = mid;
        }
        sb[threadIdx.x] = lo;
    }
    __syncthreads();
    int start = sb[0], end = sb[1];
    int t = threadIdx.x;
    int f = t & 127, r2 = t >> 7;  // r2 in 0..3
    float vmax = -INFINITY, vmin = INFINITY, vsum = 0.f;
    if (f < 124) {
        for (int node = start + r * 4 + r2; node < end; node += PARTS * 4) {
            float v = h[(size_t)node * 124 + f];
            vmax = fmaxf(vmax, v);
            vmin = fminf(vmin, v);
            vsum += v;
        }
    }
    __shared__ float smax[4][128], smin[4][128], ssum[4][128];
    smax[r2][f] = vmax; smin[r2][f] = vmin; ssum[r2][f] = vsum;
    __syncthreads();
    if (r2 == 0) {
        #pragma unroll
        for (int k = 1; k < 4; k++) {
            vmax = fmaxf(vmax, smax[k][f]);
            vmin = fminf(vmin, smin[k][f]);
            vsum += ssum[k][f];
        }
        int idx = (g * PARTS + r) * 128 + f;
        pmax[idx] = vmax; pmin[idx] = vmin; psum[idx] = vsum;
    }
}

// ---------------------------------------------------------------------------
// Fused pooling-fold + head, one block per graph.
// ---------------------------------------------------------------------------
__global__ __launch_bounds__(256) void k_head(
    const float* __restrict__ pmax, const float* __restrict__ pmin,
    const float* __restrict__ psum, const int* __restrict__ batch,
    const float* __restrict__ nn2W, const float* __restrict__ nn2b,
    const float* __restrict__ W4,   const float* __restrict__ b4,
    const float* __restrict__ nn3W, const float* __restrict__ nn3b,
    const float* __restrict__ nn4W, const float* __restrict__ nn4b,
    float* __restrict__ out, int n) {
    int g = blockIdx.x, tid = threadIdx.x;
    int lane = tid & 63, w = tid >> 6;
    __shared__ float lg[496];
    __shared__ float part[4][64];
    __shared__ int sb[2];
    if (tid < 2) {
        int target = g + tid;
        int lo = 0, hi = n;
        while (lo < hi) {
            int mid = (lo + hi) >> 1;
            if (batch[mid] < target) lo = mid + 1; else hi = mid;
        }
        sb[tid] = lo;
    }
    __syncthreads();
    if (tid < 124) {
        float vmax = -INFINITY, vmin = INFINITY, vsum = 0.f;
        #pragma unroll 4
        for (int r = 0; r < PARTS; r++) {
            int idx = (g * PARTS + r) * 128 + tid;
            vmax = fmaxf(vmax, pmax[idx]);
            vmin = fminf(vmin, pmin[idx]);
            vsum += psum[idx];
        }
        int cnt = sb[1] - sb[0];
        float a = (cnt > 0) ? vmax : 0.f;
        float b = (cnt > 0) ? vmin : 0.f;
        lg[tid]       = fmaxf(a, 0.f);
        lg[124 + tid] = fmaxf(b, 0.f);
        lg[248 + tid] = fmaxf(vsum, 0.f);
        lg[372 + tid] = fmaxf(vsum / fmaxf((float)cnt, 1.f), 0.f);
    }
    __syncthreads();
    float acc = 0.f;
    int k0 = w * 124;
    #pragma unroll 4
    for (int k = k0; k < k0 + 124; k++)
        acc += lg[k] * nn2W[k * 64 + lane];
    part[w][lane] = acc;
    __syncthreads();
    if (w == 0) {
        float g1 = part[0][lane] + part[1][lane] + part[2][lane] + part[3][lane]
                 + nn2b[lane];
        float acc2 = (lane < 32) ? b4[lane] : 0.f;
        #pragma unroll 8
        for (int k = 0; k < 64; k++) {
            float v = __shfl(g1, k);
            if (lane < 32) acc2 += v * W4[k * 32 + lane];
        }
        float g2 = fmaxf(acc2, 0.f);
        float acc3 = (lane < 16) ? nn3b[lane] : 0.f;
        #pragma unroll 8
        for (int k = 0; k < 32; k++) {
            float v = __shfl(g2, k);
            if (lane < 16) acc3 += v * nn3W[k * 16 + lane];
        }
        float g3 = fmaxf(acc3, 0.f);
        float p = (lane < 16) ? g3 * nn4W[lane] : 0.f;
        p += __shfl_xor(p, 8);
        p += __shfl_xor(p, 4);
        p += __shfl_xor(p, 2);
        p += __shfl_xor(p, 1);
        if (lane == 0) out[g] = p + nn4b[0];
    }
}

// ---------------------------------------------------------------------------
extern "C" void kernel_launch(void* const* d_in, const int* in_sizes, int n_in,
                              void* d_out, int out_size, void* d_ws, size_t ws_size,
                              hipStream_t stream) {
    const int N = N_NODES, E = N_EDGES, G = N_GRAPHS;

    const float* x     = (const float*)d_in[0];
    const int*   ei    = (const int*)d_in[1];
    const int*   batch = (const int*)d_in[2];
    const float* W1    = (const float*)d_in[3];
    const float* b1    = (const float*)d_in[4];
    const float* W2    = (const float*)d_in[5];
    const float* b2    = (const float*)d_in[6];
    const float* nn1W  = (const float*)d_in[7];
    const float* nn1b  = (const float*)d_in[8];
    const float* nn2W  = (const float*)d_in[9];
    const float* nn2b  = (const float*)d_in[10];
    const float* W4    = (const float*)d_in[11];
    const float* b4    = (const float*)d_in[12];
    const float* nn3W  = (const float*)d_in[13];
    const float* nn3b  = (const float*)d_in[14];
    const float* nn4W  = (const float*)d_in[15];
    const float* nn4b  = (const float*)d_in[16];

    const int* src = ei;       // edge_index[0]
    const int* dst = ei + E;   // edge_index[1]

    char* ws = (char*)d_ws;
    size_t off = 0;
    auto alloc = [&](size_t bytes) -> char* {
        char* p = ws + off;
        off += (bytes + 255) & ~(size_t)255;
        return p;
    };
    int*   hcnt    = (int*)  alloc((size_t)BA * NBK * 4);
    int*   bstart  = (int*)  alloc((NBK + 1) * 4);
    int2*  pairs   = (int2*) alloc((size_t)E * 8);
    int*   row_ptr = (int*)  alloc((size_t)(N + 1) * 4);
    float* dinv    = (float*)alloc((size_t)N * 4);
    int*   csr_src = (int*)  alloc((size_t)E * 4);
    float* y0      = (float*)alloc((size_t)N * 8 * 4);
    float* y1      = (float*)alloc((size_t)N * 32 * 4);
    float* sv      = (float*)alloc((size_t)N * 32 * 4);
    float* h       = (float*)alloc((size_t)N * 124 * 4);
    float* pmax    = (float*)alloc((size_t)G * PARTS * 128 * 4);
    float* pmin    = (float*)alloc((size_t)G * PARTS * 128 * 4);
    float* psum    = (float*)alloc((size_t)G * PARTS * 128 * 4);
    (void)ws_size;

    float* out = (float*)d_out;

    k_hist<<<BA, 1024, 0, stream>>>(dst, hcnt, E);
    k_bstart<<<1, 256, 0, stream>>>(hcnt, bstart, row_ptr, E);
    k_bdist<<<NBK, 256, 0, stream>>>(hcnt, bstart);
    k_scatter<<<BA, 1024, 0, stream>>>(src, dst, hcnt, pairs, E);
    k_bucket<<<NBK, 512, 0, stream>>>(pairs, bstart, x, row_ptr, dinv, y0, csr_src, N);
    k_agg1<<<(N + 3) / 4, 256, 0, stream>>>(row_ptr, csr_src, y0, dinv, W1, b1, y1, N);
    k_agg2g<<<(N + 3) / 4, 256, 0, stream>>>(row_ptr, csr_src, y1, dinv, sv, N);
    k_l2mm<<<(N + 127) / 128, 512, 0, stream>>>(sv, W2, b2, nn1W, nn1b, h, N);
    k_pool_a<<<G * PARTS, 512, 0, stream>>>(h, batch, pmax, pmin, psum, N);
    k_head<<<G, 256, 0, stream>>>(pmax, pmin, psum, batch, nn2W, nn2b, W4, b4,
                                  nn3W, nn3b, nn4W, nn4b, out, N);
}